// Round 3
// baseline (494.525 us; speedup 1.0000x reference)
//
#include <hip/hip_runtime.h>
#include <math.h>

// Problem constants (ODConv 1x1, eval mode)
#define BATCH 32
#define CIN   512
#define COUT  512
#define HW    3136     // 56*56 = 49*64
#define KNUM  4
#define ADIM  32
#define EPS   1e-5f

// ---------------- workspace layout (bytes) ----------------
static constexpr size_t XT_OFF    = 0;           // bf16 [B][HW][CIN]  102,760,448
static constexpr size_t WF_OFF    = 102760448;   // bf16 [B][COUT][CIN] 16,777,216
static constexpr size_t PART_OFF  = 119537664;   // f32 [B][49][512]    3,211,264
static constexpr size_t CH_OFF    = 122748928;   // f32 [B][CIN]
static constexpr size_t FLINV_OFF = 122814464;   // f32 [B][COUT]
static constexpr size_t KN_OFF    = 122880000;   // f32 [B][K]

typedef __attribute__((ext_vector_type(8))) short short8;   // 8 bf16 (MFMA A/B frag)
typedef __attribute__((ext_vector_type(4))) float float4v;  // MFMA C/D frag

typedef const unsigned int __attribute__((address_space(1)))* gas_ptr;
typedef unsigned int __attribute__((address_space(3)))* lds_ptr;

#define WAITVM(N) asm volatile("s_waitcnt vmcnt(" #N ")" ::: "memory")
#define WAITLGKM0() asm volatile("s_waitcnt lgkmcnt(0)" ::: "memory")

__device__ __forceinline__ unsigned short f2bf(float f) {
  unsigned int u = __float_as_uint(f);
  u += 0x7FFFu + ((u >> 16) & 1u);   // RNE
  return (unsigned short)(u >> 16);
}

// ---------------- K1: x [b][c][p] -> xT bf16 [b][p][c], partial pool sums ----------------
// One 64p x 128c pass per block, ONE barrier, granule-XOR-swizzled LDS (16B granules,
// key = p>>2): transposed ushort2 column writes exactly 2-way (free), b128 reads tile
// banks uniformly. 256-B coalesced segments on both f32 loads and bf16 stores.
__global__ __launch_bounds__(256) void transpose_pool(
    const float* __restrict__ x, unsigned short* __restrict__ xT,
    float* __restrict__ part) {
  __shared__ unsigned short T[64 * 128];   // [p][c] 16 KB, granule-swizzled
  const int pb = blockIdx.x * 64;          // p base (HW = 49*64)
  const int cb = blockIdx.y * 128;         // c base (CIN = 4*128)
  const int b  = blockIdx.z;
  const int t  = threadIdx.x;
  const int pq = t & 15;                   // p-quad index (16 quads of 4 p)
  const int ch = t >> 4;                   // c-pair-within-group 0..15

  float s[4][2];
  #pragma unroll
  for (int it = 0; it < 4; ++it) {
    const int cp = it * 16 + ch;           // c-pair 0..63
    const int c  = cb + cp * 2;
    const float* xp = x + (size_t)(b * CIN + c) * HW + pb + pq * 4;
    float4 v0 = *(const float4*)(xp);      // 16 lanes x 16B = 256B segments
    float4 v1 = *(const float4*)(xp + HW);
    s[it][0] = v0.x + v0.y + v0.z + v0.w;
    s[it][1] = v1.x + v1.y + v1.z + v1.w;
    const int dbase = (((cp >> 2) ^ pq) & 15) * 4 + (cp & 3);  // dword within row
    const float* f0 = (const float*)&v0;
    const float* f1 = (const float*)&v1;
    #pragma unroll
    for (int j = 0; j < 4; ++j) {
      const int p = pq * 4 + j;
      unsigned int w = (unsigned int)f2bf(f0[j]) |
                       ((unsigned int)f2bf(f1[j]) << 16);
      *(unsigned int*)&T[p * 128 + dbase * 2] = w;   // 2-way bank access (free)
    }
  }
  #pragma unroll
  for (int it = 0; it < 4; ++it) {
    #pragma unroll
    for (int e = 0; e < 2; ++e) {
      float v = s[it][e];
      #pragma unroll
      for (int off = 8; off > 0; off >>= 1) v += __shfl_down(v, off, 16);
      if (pq == 0)
        part[((size_t)b * 49 + blockIdx.x) * 512 + cb + (it * 16 + ch) * 2 + e] = v;
    }
  }
  __syncthreads();
  const int cg = t & 15;                   // c-granule (8 c's)
  const int rb = t >> 4;
  #pragma unroll
  for (int itr = 0; itr < 4; ++itr) {
    const int p = rb + itr * 16;
    const int key = (p >> 2) & 15;
    uint4 r = *(const uint4*)&T[p * 128 + ((cg ^ key) & 15) * 8];
    *(uint4*)(xT + (size_t)(b * HW + pb + p) * CIN + cb + cg * 8) = r;
  }
}

// ---------------- K2: all attention heads fused; grid = (BATCH), 256 thr ----------------
__global__ __launch_bounds__(256) void attn_all(
    const float* __restrict__ part, const float* __restrict__ fc_w,
    const float* __restrict__ abn_g, const float* __restrict__ abn_b,
    const float* __restrict__ abn_m, const float* __restrict__ abn_v,
    const float* __restrict__ kn_w, const float* __restrict__ kn_b,
    const float* __restrict__ ch_w, const float* __restrict__ ch_b,
    const float* __restrict__ fl_w, const float* __restrict__ fl_b,
    const float* __restrict__ bn_g, const float* __restrict__ bn_v,
    float* __restrict__ ch_out, float* __restrict__ flinv_out,
    float* __restrict__ kn_out) {
  __shared__ float pooledS[CIN];
  __shared__ float hs[ADIM];
  const int b = blockIdx.x, t = threadIdx.x;
  #pragma unroll
  for (int idx = t; idx < CIN; idx += 256) {
    float s = 0.f;
    for (int j = 0; j < 49; ++j) s += part[((size_t)b * 49 + j) * 512 + idx];
    pooledS[idx] = s;
  }
  __syncthreads();
  {
    const int a = t >> 3, pz = t & 7;
    const float* fr = fc_w + a * CIN + pz * 64;
    const float* pp = pooledS + pz * 64;
    float s = 0.f;
    #pragma unroll 8
    for (int c = 0; c < 64; ++c) s += pp[c] * fr[c];
    #pragma unroll
    for (int off = 4; off > 0; off >>= 1) s += __shfl_down(s, off, 8);
    if (pz == 0) {
      s *= (1.0f / (float)HW);
      float vv = (s - abn_m[a]) * (abn_g[a] * rsqrtf(abn_v[a] + EPS)) + abn_b[a];
      hs[a] = fmaxf(vv, 0.f);
    }
  }
  __syncthreads();
  if (t == 0) {   // kn softmax (tiny)
    float lg[KNUM]; float mx = -1e30f;
    for (int k = 0; k < KNUM; ++k) {
      float acc = kn_b[k];
      for (int aa = 0; aa < ADIM; ++aa) acc += hs[aa] * kn_w[k * ADIM + aa];
      lg[k] = acc; mx = fmaxf(mx, acc);
    }
    float ssum = 0.f;
    for (int k = 0; k < KNUM; ++k) { lg[k] = expf(lg[k] - mx); ssum += lg[k]; }
    for (int k = 0; k < KNUM; ++k) kn_out[b * KNUM + k] = lg[k] / ssum;
  }
  #pragma unroll
  for (int c = t; c < CIN; c += 256) {
    const float* wr = ch_w + c * ADIM;
    float acc = ch_b[c];
    #pragma unroll
    for (int aa = 0; aa < ADIM; ++aa) acc += hs[aa] * wr[aa];
    ch_out[b * CIN + c] = 1.f / (1.f + expf(-acc));
  }
  #pragma unroll
  for (int o = t; o < COUT; o += 256) {
    const float* wr = fl_w + o * ADIM;
    float acc = fl_b[o];
    #pragma unroll
    for (int aa = 0; aa < ADIM; ++aa) acc += hs[aa] * wr[aa];
    float sig = 1.f / (1.f + expf(-acc));
    flinv_out[b * COUT + o] = sig * (bn_g[o] * rsqrtf(bn_v[o] + EPS));
  }
}

// ---------------- K3: Wf[b][o][c] = bf16( flinv[b][o] * ch[b][c] * sum_k kn[b][k]*w[k][o][c] )
__global__ __launch_bounds__(256) void build_wf(
    const float* __restrict__ weight, const float* __restrict__ kn,
    const float* __restrict__ ch, const float* __restrict__ flinv,
    unsigned short* __restrict__ Wf) {
  const int och = blockIdx.x, b = blockIdx.y, t = threadIdx.x;
  const int o0 = och * 16;
  const float k0 = kn[b * KNUM + 0], k1 = kn[b * KNUM + 1];
  const float k2 = kn[b * KNUM + 2], k3 = kn[b * KNUM + 3];
  #pragma unroll
  for (int i = 0; i < 8; ++i) {
    int cell = i * 1024 + t * 4;
    int ol = cell >> 9, c = cell & 511;
    int o = o0 + ol;
    float fi = flinv[b * COUT + o];
    const float* wp = weight + (size_t)o * CIN + c;
    float4 w0 = *(const float4*)(wp);
    float4 w1 = *(const float4*)(wp + 1 * CIN * COUT);
    float4 w2 = *(const float4*)(wp + 2 * CIN * COUT);
    float4 w3 = *(const float4*)(wp + 3 * CIN * COUT);
    float4 cv = *(const float4*)(ch + b * CIN + c);
    ushort4 r;
    r.x = f2bf((k0 * w0.x + k1 * w1.x + k2 * w2.x + k3 * w3.x) * cv.x * fi);
    r.y = f2bf((k0 * w0.y + k1 * w1.y + k2 * w2.y + k3 * w3.y) * cv.y * fi);
    r.z = f2bf((k0 * w0.z + k1 * w1.z + k2 * w2.z + k3 * w3.z) * cv.z * fi);
    r.w = f2bf((k0 * w0.w + k1 * w1.w + k2 * w2.w + k3 * w3.w) * cv.w * fi);
    *(ushort4*)(Wf + (size_t)(b * COUT + o) * CIN + c) = r;
  }
}

// ---------------- K4: y[b][o][p] = sum_c Wf[b][o][c] * xT[b][p][c] + BN shift ----------------
// R3: 128x128 tile, BK=32, ring-2 LDS (2 x 16 KB = 32 KB total -> occupancy preserved at
// 4 blocks/CU = 16 waves/CU, 4 independent barrier domains), COUNTED vmcnt(4): tile t+1's
// 4 stage loads are issued one full iteration before their wait, so HBM/L2 latency hides
// under compute instead of the m97-style vmcnt(0) drain (the known ~20% stall). R2's
// lesson applied: never trade occupancy for pipeline depth (m132 trap) — this keeps R1's
// occupancy AND adds the pipeline. lgkmcnt(0) before the trailing barrier closes the
// ds_read-vs-overwrite window. Granule-XOR swizzle (key=(row>>1)&3) applied to the
// per-lane GLOBAL source (gload_lds dest stays lane-linear), un-applied at frag-read ->
// 0 bank conflicts (validated in R2). Accumulation order over c identical to R1 ->
// bit-identical output. Grid (ot,pt,b), ot fastest: 4 consecutive blocks share one xT tile.
__global__ __launch_bounds__(256, 4) void gemm_kernel(
    const unsigned short* __restrict__ xT, const unsigned short* __restrict__ Wf,
    const float* __restrict__ bn_g, const float* __restrict__ bn_b,
    const float* __restrict__ bn_m, const float* __restrict__ bn_v,
    float* __restrict__ y) {
  __shared__ unsigned short L[2 * 8192];   // 2 bufs x (A 4096 + B 4096 shorts) = 32 KB
  const int ot = blockIdx.x, pt = blockIdx.y, b = blockIdx.z;
  const int o0 = ot * 128, p0 = pt * 128;
  const int t = threadIdx.x;
  const int wave = t >> 6, lane = t & 63;
  const int wm = wave & 1, wn = wave >> 1;   // wave tile: o 64 x p 64

  const unsigned short* Ab = Wf + (size_t)b * COUT * CIN;
  const unsigned short* Bb = xT + (size_t)b * HW * CIN;

  // staging: per K-tile (BK=32), A = 128 rows x 32 c = 8 KB = 8 chunks of 16 rows;
  // wave stages chunks {wave, wave+4} for A and B (2+2 = 4 gload_lds per lane per tile).
  // Lane l -> row rr = l>>2, granule slot l&3; source granule pre-permuted by
  // key = (row>>1)&3 == (l>>3)&3, so LDS slot g holds global granule g ^ key.
  const int rr = lane >> 2;
  const int gp = (lane & 3) ^ ((lane >> 3) & 3);
  const unsigned short* aS[2];
  const unsigned short* bS[2];
  int dOff[2];
  #pragma unroll
  for (int q = 0; q < 2; ++q) {
    const int m = q * 4 + wave;            // 16-row chunk 0..7
    dOff[q] = m * 512;                     // shorts; wave-uniform LDS base
    aS[q] = Ab + (size_t)(o0 + m * 16 + rr) * CIN + gp * 8;
    int brow = p0 + m * 16 + rr;
    if (brow > HW - 1) brow = HW - 1;      // clamp tail p-tile (stores predicated)
    bS[q] = Bb + (size_t)brow * CIN + gp * 8;
  }

  float4v acc[4][4];
  #pragma unroll
  for (int i = 0; i < 4; ++i)
    #pragma unroll
    for (int j = 0; j < 4; ++j)
      #pragma unroll
      for (int r = 0; r < 4; ++r) acc[i][j][r] = 0.f;

  const int arow = lane & 15;              // fragment m/n index
  const int kgrp = lane >> 4;              // k-octet 0..3
  const int sl = (kgrp ^ ((arow >> 1) & 3)) * 8;   // un-swizzled LDS granule (shorts)

  auto stage = [&](int tt) {
    const int bufb = (tt & 1) * 8192;
    const int co = tt * 32;                // c advance in shorts
    #pragma unroll
    for (int q = 0; q < 2; ++q)
      __builtin_amdgcn_global_load_lds((gas_ptr)(const void*)(aS[q] + co),
          (lds_ptr)(void*)&L[bufb + dOff[q]], 16, 0, 0);
    #pragma unroll
    for (int q = 0; q < 2; ++q)
      __builtin_amdgcn_global_load_lds((gas_ptr)(const void*)(bS[q] + co),
          (lds_ptr)(void*)&L[bufb + 4096 + dOff[q]], 16, 0, 0);
  };

  auto compute = [&](int tt) {
    const int bufb = (tt & 1) * 8192;
    short8 af[4], bv[4];
    #pragma unroll
    for (int i = 0; i < 4; ++i)
      af[i] = *(const short8*)&L[bufb + (wm * 64 + i * 16 + arow) * 32 + sl];
    #pragma unroll
    for (int j = 0; j < 4; ++j)
      bv[j] = *(const short8*)&L[bufb + 4096 + (wn * 64 + j * 16 + arow) * 32 + sl];
    #pragma unroll
    for (int i = 0; i < 4; ++i)
      #pragma unroll
      for (int j = 0; j < 4; ++j)
        acc[i][j] = __builtin_amdgcn_mfma_f32_16x16x32_bf16(af[i], bv[j], acc[i][j], 0, 0, 0);
  };

  // ring-2 pipeline, counted vmcnt: tile t's wait covers loads issued one iter earlier.
  stage(0);
  #pragma unroll 1
  for (int tt = 0; tt < 15; ++tt) {
    stage(tt + 1);                         // 4 loads into buf (tt+1)&1
    WAITVM(4);                             // tile tt's 4 loads landed; tt+1's in flight
    __builtin_amdgcn_s_barrier();          // all waves' tile-tt stages visible
    compute(tt);
    WAITLGKM0();                           // ds_reads retired before buf reuse
    __builtin_amdgcn_s_barrier();          // all waves done reading buf tt&1
  }
  WAITVM(0);
  __builtin_amdgcn_s_barrier();
  compute(15);

  // epilogue: C/D map col=lane&15 (p), row=(lane>>4)*4+reg (o); BN folded inline
  const int rowq = (lane >> 4) * 4;
  const int coln = lane & 15;
  #pragma unroll
  for (int i = 0; i < 4; ++i) {
    const int obase = o0 + wm * 64 + i * 16 + rowq;
    float bet[4];
    #pragma unroll
    for (int r = 0; r < 4; ++r) {
      const int o = obase + r;
      const float inv = bn_g[o] * rsqrtf(bn_v[o] + EPS);
      bet[r] = bn_b[o] - bn_m[o] * inv;
    }
    #pragma unroll
    for (int j = 0; j < 4; ++j) {
      const int p = p0 + wn * 64 + j * 16 + coln;
      if (p < HW) {
        #pragma unroll
        for (int r = 0; r < 4; ++r)
          y[(size_t)(b * COUT + obase + r) * HW + p] = acc[i][j][r] + bet[r];
      }
    }
  }
}

// ---------------- host ----------------
extern "C" void kernel_launch(void* const* d_in, const int* in_sizes, int n_in,
                              void* d_out, int out_size, void* d_ws, size_t ws_size,
                              hipStream_t stream) {
  (void)in_sizes; (void)n_in; (void)out_size; (void)ws_size;
  const float* x     = (const float*)d_in[0];
  const float* fc_w  = (const float*)d_in[1];
  const float* abn_g = (const float*)d_in[2];
  const float* abn_b = (const float*)d_in[3];
  const float* abn_m = (const float*)d_in[4];
  const float* abn_v = (const float*)d_in[5];
  const float* ch_w  = (const float*)d_in[6];
  const float* ch_b  = (const float*)d_in[7];
  const float* fl_w  = (const float*)d_in[8];
  const float* fl_b  = (const float*)d_in[9];
  const float* kn_w  = (const float*)d_in[10];
  const float* kn_b  = (const float*)d_in[11];
  const float* weight= (const float*)d_in[12];
  const float* bn_g  = (const float*)d_in[13];
  const float* bn_b  = (const float*)d_in[14];
  const float* bn_m  = (const float*)d_in[15];
  const float* bn_v  = (const float*)d_in[16];
  float* out = (float*)d_out;

  char* ws = (char*)d_ws;
  unsigned short* xT = (unsigned short*)(ws + XT_OFF);
  unsigned short* Wf = (unsigned short*)(ws + WF_OFF);
  float* part  = (float*)(ws + PART_OFF);
  float* ch    = (float*)(ws + CH_OFF);
  float* flinv = (float*)(ws + FLINV_OFF);
  float* kn    = (float*)(ws + KN_OFF);

  transpose_pool<<<dim3(49, 4, BATCH), 256, 0, stream>>>(x, xT, part);
  attn_all<<<BATCH, 256, 0, stream>>>(part, fc_w, abn_g, abn_b, abn_m, abn_v,
                                      kn_w, kn_b, ch_w, ch_b, fl_w, fl_b,
                                      bn_g, bn_v, ch, flinv, kn);
  build_wf<<<dim3(32, BATCH), 256, 0, stream>>>(weight, kn, ch, flinv, Wf);
  gemm_kernel<<<dim3(4, 25, BATCH), 256, 0, stream>>>(xT, Wf, bn_g, bn_b, bn_m, bn_v, out);
}

// Round 4
// 477.124 us; speedup vs baseline: 1.0365x; 1.0365x over previous
//
#include <hip/hip_runtime.h>
#include <math.h>

// Problem constants (ODConv 1x1, eval mode)
#define BATCH 32
#define CIN   512
#define COUT  512
#define HW    3136     // 56*56 = 49*64
#define KNUM  4
#define ADIM  32
#define EPS   1e-5f

// ---------------- workspace layout (bytes) ----------------
static constexpr size_t XT_OFF    = 0;           // bf16 [B][HW][CIN]  102,760,448
static constexpr size_t WF_OFF    = 102760448;   // bf16 [B][COUT][CIN] 16,777,216
static constexpr size_t PART_OFF  = 119537664;   // f32 [B][49][512]    3,211,264
static constexpr size_t CH_OFF    = 122748928;   // f32 [B][CIN]
static constexpr size_t FLINV_OFF = 122814464;   // f32 [B][COUT]
static constexpr size_t KN_OFF    = 122880000;   // f32 [B][K]

typedef __attribute__((ext_vector_type(8))) short short8;   // 8 bf16 (MFMA A/B frag)
typedef __attribute__((ext_vector_type(4))) float float4v;  // MFMA C/D frag

typedef const unsigned int __attribute__((address_space(1)))* gas_ptr;
typedef unsigned int __attribute__((address_space(3)))* lds_ptr;

__device__ __forceinline__ unsigned short f2bf(float f) {
  unsigned int u = __float_as_uint(f);
  u += 0x7FFFu + ((u >> 16) & 1u);   // RNE
  return (unsigned short)(u >> 16);
}

// ---------------- K1: x [b][c][p] -> xT bf16 [b][p][c], partial pool sums ----------------
// One 64p x 128c pass per block, ONE barrier, granule-XOR-swizzled LDS (16B granules,
// key = p>>2): transposed ushort2 column writes exactly 2-way (free), b128 reads tile
// banks uniformly. 256-B coalesced segments on both f32 loads and bf16 stores.
__global__ __launch_bounds__(256) void transpose_pool(
    const float* __restrict__ x, unsigned short* __restrict__ xT,
    float* __restrict__ part) {
  __shared__ unsigned short T[64 * 128];   // [p][c] 16 KB, granule-swizzled
  const int pb = blockIdx.x * 64;          // p base (HW = 49*64)
  const int cb = blockIdx.y * 128;         // c base (CIN = 4*128)
  const int b  = blockIdx.z;
  const int t  = threadIdx.x;
  const int pq = t & 15;                   // p-quad index (16 quads of 4 p)
  const int ch = t >> 4;                   // c-pair-within-group 0..15

  float s[4][2];
  #pragma unroll
  for (int it = 0; it < 4; ++it) {
    const int cp = it * 16 + ch;           // c-pair 0..63
    const int c  = cb + cp * 2;
    const float* xp = x + (size_t)(b * CIN + c) * HW + pb + pq * 4;
    float4 v0 = *(const float4*)(xp);      // 16 lanes x 16B = 256B segments
    float4 v1 = *(const float4*)(xp + HW);
    s[it][0] = v0.x + v0.y + v0.z + v0.w;
    s[it][1] = v1.x + v1.y + v1.z + v1.w;
    const int dbase = (((cp >> 2) ^ pq) & 15) * 4 + (cp & 3);  // dword within row
    const float* f0 = (const float*)&v0;
    const float* f1 = (const float*)&v1;
    #pragma unroll
    for (int j = 0; j < 4; ++j) {
      const int p = pq * 4 + j;
      unsigned int w = (unsigned int)f2bf(f0[j]) |
                       ((unsigned int)f2bf(f1[j]) << 16);
      *(unsigned int*)&T[p * 128 + dbase * 2] = w;   // 2-way bank access (free)
    }
  }
  #pragma unroll
  for (int it = 0; it < 4; ++it) {
    #pragma unroll
    for (int e = 0; e < 2; ++e) {
      float v = s[it][e];
      #pragma unroll
      for (int off = 8; off > 0; off >>= 1) v += __shfl_down(v, off, 16);
      if (pq == 0)
        part[((size_t)b * 49 + blockIdx.x) * 512 + cb + (it * 16 + ch) * 2 + e] = v;
    }
  }
  __syncthreads();
  const int cg = t & 15;                   // c-granule (8 c's)
  const int rb = t >> 4;
  #pragma unroll
  for (int itr = 0; itr < 4; ++itr) {
    const int p = rb + itr * 16;
    const int key = (p >> 2) & 15;
    uint4 r = *(const uint4*)&T[p * 128 + ((cg ^ key) & 15) * 8];
    *(uint4*)(xT + (size_t)(b * HW + pb + p) * CIN + cb + cg * 8) = r;
  }
}

// ---------------- K2: all attention heads fused; grid = (BATCH), 256 thr ----------------
__global__ __launch_bounds__(256) void attn_all(
    const float* __restrict__ part, const float* __restrict__ fc_w,
    const float* __restrict__ abn_g, const float* __restrict__ abn_b,
    const float* __restrict__ abn_m, const float* __restrict__ abn_v,
    const float* __restrict__ kn_w, const float* __restrict__ kn_b,
    const float* __restrict__ ch_w, const float* __restrict__ ch_b,
    const float* __restrict__ fl_w, const float* __restrict__ fl_b,
    const float* __restrict__ bn_g, const float* __restrict__ bn_v,
    float* __restrict__ ch_out, float* __restrict__ flinv_out,
    float* __restrict__ kn_out) {
  __shared__ float pooledS[CIN];
  __shared__ float hs[ADIM];
  const int b = blockIdx.x, t = threadIdx.x;
  #pragma unroll
  for (int idx = t; idx < CIN; idx += 256) {
    float s = 0.f;
    for (int j = 0; j < 49; ++j) s += part[((size_t)b * 49 + j) * 512 + idx];
    pooledS[idx] = s;
  }
  __syncthreads();
  {
    const int a = t >> 3, pz = t & 7;
    const float* fr = fc_w + a * CIN + pz * 64;
    const float* pp = pooledS + pz * 64;
    float s = 0.f;
    #pragma unroll 8
    for (int c = 0; c < 64; ++c) s += pp[c] * fr[c];
    #pragma unroll
    for (int off = 4; off > 0; off >>= 1) s += __shfl_down(s, off, 8);
    if (pz == 0) {
      s *= (1.0f / (float)HW);
      float vv = (s - abn_m[a]) * (abn_g[a] * rsqrtf(abn_v[a] + EPS)) + abn_b[a];
      hs[a] = fmaxf(vv, 0.f);
    }
  }
  __syncthreads();
  if (t == 0) {   // kn softmax (tiny)
    float lg[KNUM]; float mx = -1e30f;
    for (int k = 0; k < KNUM; ++k) {
      float acc = kn_b[k];
      for (int aa = 0; aa < ADIM; ++aa) acc += hs[aa] * kn_w[k * ADIM + aa];
      lg[k] = acc; mx = fmaxf(mx, acc);
    }
    float ssum = 0.f;
    for (int k = 0; k < KNUM; ++k) { lg[k] = expf(lg[k] - mx); ssum += lg[k]; }
    for (int k = 0; k < KNUM; ++k) kn_out[b * KNUM + k] = lg[k] / ssum;
  }
  #pragma unroll
  for (int c = t; c < CIN; c += 256) {
    const float* wr = ch_w + c * ADIM;
    float acc = ch_b[c];
    #pragma unroll
    for (int aa = 0; aa < ADIM; ++aa) acc += hs[aa] * wr[aa];
    ch_out[b * CIN + c] = 1.f / (1.f + expf(-acc));
  }
  #pragma unroll
  for (int o = t; o < COUT; o += 256) {
    const float* wr = fl_w + o * ADIM;
    float acc = fl_b[o];
    #pragma unroll
    for (int aa = 0; aa < ADIM; ++aa) acc += hs[aa] * wr[aa];
    float sig = 1.f / (1.f + expf(-acc));
    flinv_out[b * COUT + o] = sig * (bn_g[o] * rsqrtf(bn_v[o] + EPS));
  }
}

// ---------------- K3: Wf[b][o][c] = bf16( flinv[b][o] * ch[b][c] * sum_k kn[b][k]*w[k][o][c] )
__global__ __launch_bounds__(256) void build_wf(
    const float* __restrict__ weight, const float* __restrict__ kn,
    const float* __restrict__ ch, const float* __restrict__ flinv,
    unsigned short* __restrict__ Wf) {
  const int och = blockIdx.x, b = blockIdx.y, t = threadIdx.x;
  const int o0 = och * 16;
  const float k0 = kn[b * KNUM + 0], k1 = kn[b * KNUM + 1];
  const float k2 = kn[b * KNUM + 2], k3 = kn[b * KNUM + 3];
  #pragma unroll
  for (int i = 0; i < 8; ++i) {
    int cell = i * 1024 + t * 4;
    int ol = cell >> 9, c = cell & 511;
    int o = o0 + ol;
    float fi = flinv[b * COUT + o];
    const float* wp = weight + (size_t)o * CIN + c;
    float4 w0 = *(const float4*)(wp);
    float4 w1 = *(const float4*)(wp + 1 * CIN * COUT);
    float4 w2 = *(const float4*)(wp + 2 * CIN * COUT);
    float4 w3 = *(const float4*)(wp + 3 * CIN * COUT);
    float4 cv = *(const float4*)(ch + b * CIN + c);
    ushort4 r;
    r.x = f2bf((k0 * w0.x + k1 * w1.x + k2 * w2.x + k3 * w3.x) * cv.x * fi);
    r.y = f2bf((k0 * w0.y + k1 * w1.y + k2 * w2.y + k3 * w3.y) * cv.y * fi);
    r.z = f2bf((k0 * w0.z + k1 * w1.z + k2 * w2.z + k3 * w3.z) * cv.z * fi);
    r.w = f2bf((k0 * w0.w + k1 * w1.w + k2 * w2.w + k3 * w3.w) * cv.w * fi);
    *(ushort4*)(Wf + (size_t)(b * COUT + o) * CIN + c) = r;
  }
}

// ---------------- K4: y[b][o][p] = sum_c Wf[b][o][c] * xT[b][p][c] + BN shift ----------------
// R4: 256x256 tile (R2's shape, best measured), BK=64, 8 waves (wave tile 128x64),
// 2 x 64 KB K-tile double-buffer (128 KB dynamic LDS, 1 block/CU). Each K-tile = 4
// phases (C-quadrants, snake order with fragment reuse: 12/4/8/0 ds_reads, 16 MFMA per
// phase, setprio around each cluster). The 8 stage loads for K-tile t+1 are issued in
// phases 0-1 of K-tile t -> ~600 cy of MFMA between issue and the block-end
// __syncthreads() drain, so the vmcnt(0) inside it completes ~free (the m97 stall was
// draining loads issued immediately before the wait, not the wait itself). Only 8
// barriers total, all __syncthreads() -> textbook-safe (WAR: frag values consumed by
// MFMA before barrier; RAW: drain+barrier). Swizzle: source-granule XOR (LDS slot s of
// row r holds global granule s^(r&7)), un-applied at frag read -> 2-way (free) banks.
// XCD-chunk swizzle: 104 consecutive logical blocks per XCD = 4 whole batches (xT+Wf
// ~4.2 MB/batch ~ L2). Accumulation order over c identical to R1-R3 -> bit-identical.
__global__ __launch_bounds__(512) void gemm_kernel(
    const unsigned short* __restrict__ xT, const unsigned short* __restrict__ Wf,
    const float* __restrict__ bn_g, const float* __restrict__ bn_b,
    const float* __restrict__ bn_m, const float* __restrict__ bn_v,
    float* __restrict__ y) {
  extern __shared__ unsigned short L[];    // 2 bufs x (A 16384 + B 16384 shorts) = 128 KB
  // XCD-chunked bijective swizzle (832 % 8 == 0)
  const int id = blockIdx.x;
  const int wg = (id & 7) * 104 + (id >> 3);
  const int ot = wg & 1;
  const int rem = wg >> 1;                 // 0..415 = 13*32
  const int pt = rem % 13;
  const int b  = rem / 13;
  const int o0 = ot * 256, p0 = pt * 256;
  const int t = threadIdx.x;
  const int wave = t >> 6, lane = t & 63;
  const int wm = wave >> 2, wn = wave & 3; // wave tile: o 128 x p 64

  const unsigned short* Ab = Wf + (size_t)b * COUT * CIN;
  const unsigned short* Bb = xT + (size_t)b * HW * CIN;

  // staging: issue q covers rows [q*64 + wave*8, +8); lane -> subrow sr = lane>>3,
  // LDS granule slot lane&7; SOURCE granule pre-permuted: gsrc = (lane&7) ^ sr, so
  // LDS[row][slot] = global granule slot ^ (row&7). 4 A-issues + 4 B-issues per K-tile.
  const int sr = lane >> 3;
  const int gsrc = (lane & 7) ^ sr;
  const unsigned short* aSrc[4];
  const unsigned short* bSrc[4];
  int aDst[4], bDst[4];
  #pragma unroll
  for (int q = 0; q < 4; ++q) {
    const int rloc = q * 64 + wave * 8;
    aDst[q] = rloc * 64;                   // shorts (row stride 64 shorts = 128 B)
    bDst[q] = 16384 + rloc * 64;
    aSrc[q] = Ab + (size_t)(o0 + rloc + sr) * CIN + gsrc * 8;
    int brow = p0 + rloc + sr;
    if (brow > HW - 1) brow = HW - 1;      // clamp tail p-tile (stores predicated)
    bSrc[q] = Bb + (size_t)brow * CIN + gsrc * 8;
  }

  auto stageA = [&](int kt) {
    const int bb = (kt & 1) * 32768;
    const int co = kt * 64;
    #pragma unroll
    for (int q = 0; q < 4; ++q)
      __builtin_amdgcn_global_load_lds((gas_ptr)(const void*)(aSrc[q] + co),
          (lds_ptr)(void*)&L[bb + aDst[q]], 16, 0, 0);
  };
  auto stageB = [&](int kt) {
    const int bb = (kt & 1) * 32768;
    const int co = kt * 64;
    #pragma unroll
    for (int q = 0; q < 4; ++q)
      __builtin_amdgcn_global_load_lds((gas_ptr)(const void*)(bSrc[q] + co),
          (lds_ptr)(void*)&L[bb + bDst[q]], 16, 0, 0);
  };

  float4v acc[8][4];
  #pragma unroll
  for (int i = 0; i < 8; ++i)
    #pragma unroll
    for (int j = 0; j < 4; ++j)
      #pragma unroll
      for (int r = 0; r < 4; ++r) acc[i][j][r] = 0.f;

  const int arow = lane & 15;              // fragment m/n index
  const int kgrp = lane >> 4;              // k-octet 0..3
  const int sl0 = ((kgrp    ) ^ (arow & 7)) * 8;  // un-swizzled slot, k-step 0 (shorts)
  const int sl1 = ((4 + kgrp) ^ (arow & 7)) * 8;  // k-step 1

  stageA(0); stageB(0);
  __syncthreads();                         // drains vmcnt(0): tile 0 visible to all

  #pragma unroll 1
  for (int kt = 0; kt < 8; ++kt) {
    const int ab  = (kt & 1) * 32768;
    const int bb2 = ab + 16384;
    short8 a0[4][2], a1[4][2], bv[4][2];

    // ---- phase 0: read A(ih=0) + B(jh=0); issue A-stage(kt+1); MFMA quadrant (0,0)
    #pragma unroll
    for (int il = 0; il < 4; ++il) {
      const int r = (wm * 128 + il * 16 + arow) * 64;
      a0[il][0] = *(const short8*)&L[ab + r + sl0];
      a0[il][1] = *(const short8*)&L[ab + r + sl1];
    }
    #pragma unroll
    for (int jl = 0; jl < 2; ++jl) {
      const int r = (wn * 64 + jl * 16 + arow) * 64;
      bv[jl][0] = *(const short8*)&L[bb2 + r + sl0];
      bv[jl][1] = *(const short8*)&L[bb2 + r + sl1];
    }
    if (kt < 7) stageA(kt + 1);
    __builtin_amdgcn_s_setprio(1);
    #pragma unroll
    for (int il = 0; il < 4; ++il)
      #pragma unroll
      for (int jl = 0; jl < 2; ++jl) {
        acc[il][jl] = __builtin_amdgcn_mfma_f32_16x16x32_bf16(a0[il][0], bv[jl][0], acc[il][jl], 0, 0, 0);
        acc[il][jl] = __builtin_amdgcn_mfma_f32_16x16x32_bf16(a0[il][1], bv[jl][1], acc[il][jl], 0, 0, 0);
      }
    __builtin_amdgcn_s_setprio(0);

    // ---- phase 1: read B(jh=1); issue B-stage(kt+1); MFMA quadrant (0,1)
    #pragma unroll
    for (int jl = 0; jl < 2; ++jl) {
      const int r = (wn * 64 + (2 + jl) * 16 + arow) * 64;
      bv[2 + jl][0] = *(const short8*)&L[bb2 + r + sl0];
      bv[2 + jl][1] = *(const short8*)&L[bb2 + r + sl1];
    }
    if (kt < 7) stageB(kt + 1);
    __builtin_amdgcn_s_setprio(1);
    #pragma unroll
    for (int il = 0; il < 4; ++il)
      #pragma unroll
      for (int jl = 0; jl < 2; ++jl) {
        acc[il][2 + jl] = __builtin_amdgcn_mfma_f32_16x16x32_bf16(a0[il][0], bv[2 + jl][0], acc[il][2 + jl], 0, 0, 0);
        acc[il][2 + jl] = __builtin_amdgcn_mfma_f32_16x16x32_bf16(a0[il][1], bv[2 + jl][1], acc[il][2 + jl], 0, 0, 0);
      }
    __builtin_amdgcn_s_setprio(0);

    // ---- phase 2: read A(ih=1); MFMA quadrant (1,1)
    #pragma unroll
    for (int il = 0; il < 4; ++il) {
      const int r = (wm * 128 + 64 + il * 16 + arow) * 64;
      a1[il][0] = *(const short8*)&L[ab + r + sl0];
      a1[il][1] = *(const short8*)&L[ab + r + sl1];
    }
    __builtin_amdgcn_s_setprio(1);
    #pragma unroll
    for (int il = 0; il < 4; ++il)
      #pragma unroll
      for (int jl = 0; jl < 2; ++jl) {
        acc[4 + il][2 + jl] = __builtin_amdgcn_mfma_f32_16x16x32_bf16(a1[il][0], bv[2 + jl][0], acc[4 + il][2 + jl], 0, 0, 0);
        acc[4 + il][2 + jl] = __builtin_amdgcn_mfma_f32_16x16x32_bf16(a1[il][1], bv[2 + jl][1], acc[4 + il][2 + jl], 0, 0, 0);
      }
    __builtin_amdgcn_s_setprio(0);

    // ---- phase 3: no reads; MFMA quadrant (1,0)
    __builtin_amdgcn_s_setprio(1);
    #pragma unroll
    for (int il = 0; il < 4; ++il)
      #pragma unroll
      for (int jl = 0; jl < 2; ++jl) {
        acc[4 + il][jl] = __builtin_amdgcn_mfma_f32_16x16x32_bf16(a1[il][0], bv[jl][0], acc[4 + il][jl], 0, 0, 0);
        acc[4 + il][jl] = __builtin_amdgcn_mfma_f32_16x16x32_bf16(a1[il][1], bv[jl][1], acc[4 + il][jl], 0, 0, 0);
      }
    __builtin_amdgcn_s_setprio(0);

    if (kt < 7) __syncthreads();           // drain (loads issued ~3 phases ago) + swap
  }

  // epilogue: C/D map col=lane&15 (p), row=(lane>>4)*4+reg (o); BN folded inline
  const int rowq = (lane >> 4) * 4;
  const int coln = lane & 15;
  #pragma unroll
  for (int i = 0; i < 8; ++i) {
    const int obase = o0 + wm * 128 + i * 16 + rowq;
    float bet[4];
    #pragma unroll
    for (int r = 0; r < 4; ++r) {
      const int o = obase + r;
      const float inv = bn_g[o] * rsqrtf(bn_v[o] + EPS);
      bet[r] = bn_b[o] - bn_m[o] * inv;
    }
    #pragma unroll
    for (int j = 0; j < 4; ++j) {
      const int p = p0 + wn * 64 + j * 16 + coln;
      if (p < HW) {
        #pragma unroll
        for (int r = 0; r < 4; ++r)
          y[(size_t)(b * COUT + obase + r) * HW + p] = acc[i][j][r] + bet[r];
      }
    }
  }
}

// ---------------- host ----------------
extern "C" void kernel_launch(void* const* d_in, const int* in_sizes, int n_in,
                              void* d_out, int out_size, void* d_ws, size_t ws_size,
                              hipStream_t stream) {
  (void)in_sizes; (void)n_in; (void)out_size; (void)ws_size;
  const float* x     = (const float*)d_in[0];
  const float* fc_w  = (const float*)d_in[1];
  const float* abn_g = (const float*)d_in[2];
  const float* abn_b = (const float*)d_in[3];
  const float* abn_m = (const float*)d_in[4];
  const float* abn_v = (const float*)d_in[5];
  const float* ch_w  = (const float*)d_in[6];
  const float* ch_b  = (const float*)d_in[7];
  const float* fl_w  = (const float*)d_in[8];
  const float* fl_b  = (const float*)d_in[9];
  const float* kn_w  = (const float*)d_in[10];
  const float* kn_b  = (const float*)d_in[11];
  const float* weight= (const float*)d_in[12];
  const float* bn_g  = (const float*)d_in[13];
  const float* bn_b  = (const float*)d_in[14];
  const float* bn_m  = (const float*)d_in[15];
  const float* bn_v  = (const float*)d_in[16];
  float* out = (float*)d_out;

  char* ws = (char*)d_ws;
  unsigned short* xT = (unsigned short*)(ws + XT_OFF);
  unsigned short* Wf = (unsigned short*)(ws + WF_OFF);
  float* part  = (float*)(ws + PART_OFF);
  float* ch    = (float*)(ws + CH_OFF);
  float* flinv = (float*)(ws + FLINV_OFF);
  float* kn    = (float*)(ws + KN_OFF);

  static bool attr_done = false;
  if (!attr_done) {
    hipFuncSetAttribute((const void*)gemm_kernel,
                        hipFuncAttributeMaxDynamicSharedMemorySize, 131072);
    attr_done = true;
  }

  transpose_pool<<<dim3(49, 4, BATCH), 256, 0, stream>>>(x, xT, part);
  attn_all<<<BATCH, 256, 0, stream>>>(part, fc_w, abn_g, abn_b, abn_m, abn_v,
                                      kn_w, kn_b, ch_w, ch_b, fl_w, fl_b,
                                      bn_g, bn_v, ch, flinv, kn);
  build_wf<<<dim3(32, BATCH), 256, 0, stream>>>(weight, kn, ch, flinv, Wf);
  gemm_kernel<<<dim3(832), dim3(512), 131072, stream>>>(xT, Wf, bn_g, bn_b, bn_m, bn_v, out);
}